// Round 1
// baseline (106.264 us; speedup 1.0000x reference)
//
#include <hip/hip_runtime.h>
#include <hip/hip_cooperative_groups.h>

namespace cg = cooperative_groups;

// APLoss reduced analytically (no O(N_POS*N) matrix materialization):
//   s_all[i] = sum_j relu(1 - f_i + y_j)^2
//   s_pos[i] = sum_j relu(1 - f_i + y_j)^2 * y_true[j]   (y_true in {0,1})
//   ua = 0.01*u_all[idx] + 0.99*s_all/N ; up = 0.01*u_pos[idx] + 0.99*s_pos/N
//   row[i] = (up*s_all - ua*s_pos)/ua^2 ; loss = sum_i row[i] / (N_POS*N)
//
// R1 post-mortem: 1-row/block streamed 268 MB through L2; row-blocking 8x
// cuts traffic to 33 MB and makes VALU (~2 us aggregate) the floor.
// R2 theory: rocprof shows the timed region is dominated by the harness's
// 256 MiB workspace poison fill (~40 us @ 83% HBM peak) + dispatch latency;
// actual kernel work is ~4 us. Only controllable lever: dispatch count.
// => fuse rows+reduce into ONE cooperative kernel (grid.sync between
// phases), with a fallback to the proven 2-kernel path if cooperative
// launch is not recordable under graph capture.

constexpr int ROWS    = 8;    // rows per block
constexpr int THREADS = 512;  // 8 waves, 2 per SIMD
constexpr int NPOS    = 2048; // fixed by problem
constexpr int NBLK    = NPOS / ROWS;  // 256 blocks = 1 per CU

// ---------------------------------------------------------------- fused ----
__global__ __launch_bounds__(THREADS) void aploss_fused(
    const float* __restrict__ y_pred,
    const float* __restrict__ y_true,
    const float* __restrict__ u_all,
    const float* __restrict__ u_pos,
    const int*   __restrict__ index_s,
    double*      __restrict__ block_part,   // NBLK doubles in d_ws
    float*       __restrict__ out,
    int n)
{
    const int i0  = blockIdx.x * ROWS;
    const int tid = threadIdx.x;

    float f[ROWS];
    #pragma unroll
    for (int r = 0; r < ROWS; ++r) f[r] = y_pred[i0 + r];  // block-uniform

    const float4* yp4 = (const float4*)y_pred;
    const float4* yt4 = (const float4*)y_true;
    const int n4 = n >> 2;  // 4096 float4 groups

    float sa[ROWS], sp[ROWS];
    #pragma unroll
    for (int r = 0; r < ROWS; ++r) { sa[r] = 0.f; sp[r] = 0.f; }

    for (int j = tid; j < n4; j += THREADS) {   // 8 groups/thread
        const float4 yp = yp4[j];
        const float4 yt = yt4[j];
        const float c0 = 1.0f + yp.x, c1 = 1.0f + yp.y;
        const float c2 = 1.0f + yp.z, c3 = 1.0f + yp.w;
        #pragma unroll
        for (int r = 0; r < ROWS; ++r) {
            float m, t;
            m = fmaxf(c0 - f[r], 0.f); sa[r] = fmaf(m, m, sa[r]); t = m * yt.x; sp[r] = fmaf(t, m, sp[r]);
            m = fmaxf(c1 - f[r], 0.f); sa[r] = fmaf(m, m, sa[r]); t = m * yt.y; sp[r] = fmaf(t, m, sp[r]);
            m = fmaxf(c2 - f[r], 0.f); sa[r] = fmaf(m, m, sa[r]); t = m * yt.z; sp[r] = fmaf(t, m, sp[r]);
            m = fmaxf(c3 - f[r], 0.f); sa[r] = fmaf(m, m, sa[r]); t = m * yt.w; sp[r] = fmaf(t, m, sp[r]);
        }
    }

    // wave-64 butterfly reduce (fp32 partials: ~5500 magnitude, rel err ~1e-6)
    #pragma unroll
    for (int off = 32; off > 0; off >>= 1) {
        #pragma unroll
        for (int r = 0; r < ROWS; ++r) {
            sa[r] += __shfl_down(sa[r], off, 64);
            sp[r] += __shfl_down(sp[r], off, 64);
        }
    }

    __shared__ float  sh_a[THREADS / 64][ROWS];
    __shared__ float  sh_p[THREADS / 64][ROWS];
    __shared__ double sh_term[ROWS];
    const int wave = tid >> 6;
    const int lane = tid & 63;
    if (lane == 0) {
        #pragma unroll
        for (int r = 0; r < ROWS; ++r) { sh_a[wave][r] = sa[r]; sh_p[wave][r] = sp[r]; }
    }
    __syncthreads();

    if (tid < ROWS) {  // thread r finalizes row i0+r in fp64
        double ta = 0.0, tp = 0.0;
        #pragma unroll
        for (int w = 0; w < THREADS / 64; ++w) {
            ta += (double)sh_a[w][tid];
            tp += (double)sh_p[w][tid];
        }
        const int idx = index_s[i0 + tid];
        const double inv_n = 1.0 / (double)n;
        const double ua = 0.01 * (double)u_all[idx] + 0.99 * (ta * inv_n);
        const double up = 0.01 * (double)u_pos[idx] + 0.99 * (tp * inv_n);
        sh_term[tid] = (up * ta - ua * tp) / (ua * ua);
    }
    __syncthreads();
    if (tid == 0) {
        double bs = 0.0;
        #pragma unroll
        for (int r = 0; r < ROWS; ++r) bs += sh_term[r];
        block_part[blockIdx.x] = bs;
    }

    cg::this_grid().sync();   // includes device-scope release/acquire

    // ---- phase 2: block 0 reduces NBLK block partials (16 KB fetch) ----
    if (blockIdx.x == 0) {
        double s = (tid < NBLK) ? block_part[tid] : 0.0;
        #pragma unroll
        for (int off = 32; off > 0; off >>= 1) s += __shfl_down(s, off, 64);
        __shared__ double sh_f[THREADS / 64];
        if (lane == 0) sh_f[wave] = s;
        __syncthreads();
        if (tid == 0) {
            double tot = 0.0;
            #pragma unroll
            for (int w = 0; w < THREADS / 64; ++w) tot += sh_f[w];
            out[0] = (float)(tot / ((double)NPOS * (double)n));
        }
    }
}

// ------------------------------------------------- fallback (R1 kernels) ----
__global__ __launch_bounds__(THREADS) void aploss_rows(
    const float* __restrict__ y_pred,
    const float* __restrict__ y_true,
    const float* __restrict__ u_all,
    const float* __restrict__ u_pos,
    const int*   __restrict__ index_s,
    double*      __restrict__ row_out,
    int n)
{
    const int i0  = blockIdx.x * ROWS;
    const int tid = threadIdx.x;

    float f[ROWS];
    #pragma unroll
    for (int r = 0; r < ROWS; ++r) f[r] = y_pred[i0 + r];

    const float4* yp4 = (const float4*)y_pred;
    const float4* yt4 = (const float4*)y_true;
    const int n4 = n >> 2;

    float sa[ROWS], sp[ROWS];
    #pragma unroll
    for (int r = 0; r < ROWS; ++r) { sa[r] = 0.f; sp[r] = 0.f; }

    for (int j = tid; j < n4; j += THREADS) {
        const float4 yp = yp4[j];
        const float4 yt = yt4[j];
        const float c0 = 1.0f + yp.x, c1 = 1.0f + yp.y;
        const float c2 = 1.0f + yp.z, c3 = 1.0f + yp.w;
        #pragma unroll
        for (int r = 0; r < ROWS; ++r) {
            float m, t;
            m = fmaxf(c0 - f[r], 0.f); sa[r] = fmaf(m, m, sa[r]); t = m * yt.x; sp[r] = fmaf(t, m, sp[r]);
            m = fmaxf(c1 - f[r], 0.f); sa[r] = fmaf(m, m, sa[r]); t = m * yt.y; sp[r] = fmaf(t, m, sp[r]);
            m = fmaxf(c2 - f[r], 0.f); sa[r] = fmaf(m, m, sa[r]); t = m * yt.z; sp[r] = fmaf(t, m, sp[r]);
            m = fmaxf(c3 - f[r], 0.f); sa[r] = fmaf(m, m, sa[r]); t = m * yt.w; sp[r] = fmaf(t, m, sp[r]);
        }
    }

    #pragma unroll
    for (int off = 32; off > 0; off >>= 1) {
        #pragma unroll
        for (int r = 0; r < ROWS; ++r) {
            sa[r] += __shfl_down(sa[r], off, 64);
            sp[r] += __shfl_down(sp[r], off, 64);
        }
    }

    __shared__ float sh_a[THREADS / 64][ROWS];
    __shared__ float sh_p[THREADS / 64][ROWS];
    const int wave = tid >> 6;
    const int lane = tid & 63;
    if (lane == 0) {
        #pragma unroll
        for (int r = 0; r < ROWS; ++r) { sh_a[wave][r] = sa[r]; sh_p[wave][r] = sp[r]; }
    }
    __syncthreads();

    if (tid < ROWS) {
        double ta = 0.0, tp = 0.0;
        #pragma unroll
        for (int w = 0; w < THREADS / 64; ++w) {
            ta += (double)sh_a[w][tid];
            tp += (double)sh_p[w][tid];
        }
        const int idx = index_s[i0 + tid];
        const double inv_n = 1.0 / (double)n;
        const double ua = 0.01 * (double)u_all[idx] + 0.99 * (ta * inv_n);
        const double up = 0.01 * (double)u_pos[idx] + 0.99 * (tp * inv_n);
        row_out[i0 + tid] = (up * ta - ua * tp) / (ua * ua);
    }
}

__global__ __launch_bounds__(256) void aploss_reduce(
    const double* __restrict__ row_terms,
    float* __restrict__ out,
    int n_pos, int n)
{
    const int tid = threadIdx.x;
    double s = 0.0;
    for (int i = tid; i < n_pos; i += 256) s += row_terms[i];
    #pragma unroll
    for (int off = 32; off > 0; off >>= 1) s += __shfl_down(s, off, 64);

    __shared__ double sh[4];
    const int wave = tid >> 6;
    const int lane = tid & 63;
    if (lane == 0) sh[wave] = s;
    __syncthreads();
    if (tid == 0) {
        double tot = sh[0] + sh[1] + sh[2] + sh[3];
        out[0] = (float)(tot / ((double)n_pos * (double)n));
    }
}

extern "C" void kernel_launch(void* const* d_in, const int* in_sizes, int n_in,
                              void* d_out, int out_size, void* d_ws, size_t ws_size,
                              hipStream_t stream) {
    const float* y_pred  = (const float*)d_in[0];
    const float* y_true  = (const float*)d_in[1];
    const float* u_all   = (const float*)d_in[2];
    const float* u_pos   = (const float*)d_in[3];
    const int*   index_s = (const int*)d_in[4];
    int n = in_sizes[0];             // 16384
    double* block_part = (double*)d_ws;   // NBLK doubles scratch
    float*  out        = (float*)d_out;

    void* args[] = { (void*)&y_pred, (void*)&y_true, (void*)&u_all,
                     (void*)&u_pos,  (void*)&index_s, (void*)&block_part,
                     (void*)&out,    (void*)&n };
    hipError_t err = hipLaunchCooperativeKernel(
        (const void*)aploss_fused, dim3(NBLK), dim3(THREADS), args, 0, stream);

    if (err != hipSuccess) {
        // cooperative node rejected (e.g. by graph capture) — proven 2-kernel path
        (void)hipGetLastError();
        aploss_rows<<<NBLK, THREADS, 0, stream>>>(
            y_pred, y_true, u_all, u_pos, index_s, block_part, n);
        aploss_reduce<<<1, 256, 0, stream>>>(block_part, out, NPOS, n);
    }
}

// Round 2
// 72.777 us; speedup vs baseline: 1.4601x; 1.4601x over previous
//
#include <hip/hip_runtime.h>

// APLoss reduced analytically (no O(N_POS*N) matrix materialization):
//   s_all[i] = sum_j relu(1 - f_i + y_j)^2
//   s_pos[i] = sum_j relu(1 - f_i + y_j)^2 * y_true[j]   (y_true in {0,1})
//   ua = 0.01*u_all[idx] + 0.99*s_all/N ; up = 0.01*u_pos[idx] + 0.99*s_pos/N
//   row[i] = (up*s_all - ua*s_pos)/ua^2 ; loss = sum_i row[i] / (N_POS*N)
//
// R1 post-mortem: 1-row/block streamed 268 MB through L2; row-blocking 8x
// cuts traffic to 33 MB and makes VALU (~2 us aggregate) the floor.
// R2 post-mortem: hipLaunchCooperativeKernel under graph capture cost +33 us
// (not a plain graph node; per-iteration cooperative validation + device
// rendezvous). Two plain kernel nodes are cheaper than one cooperative
// launch. REVERTED to the proven R0 structure.
// Budget: ~40 us harness ws-poison fill (83% HBM peak, uncontrollable)
// + ~25-30 us harness reset()/restore dispatches + ~4-6 us kernel work.

constexpr int ROWS    = 8;    // rows per block
constexpr int THREADS = 512;  // 8 waves, 2 per SIMD

__global__ __launch_bounds__(THREADS) void aploss_rows(
    const float* __restrict__ y_pred,
    const float* __restrict__ y_true,
    const float* __restrict__ u_all,
    const float* __restrict__ u_pos,
    const int*   __restrict__ index_s,
    double*      __restrict__ row_out,
    int n)
{
    const int i0  = blockIdx.x * ROWS;
    const int tid = threadIdx.x;

    float f[ROWS];
    #pragma unroll
    for (int r = 0; r < ROWS; ++r) f[r] = y_pred[i0 + r];  // block-uniform

    const float4* yp4 = (const float4*)y_pred;
    const float4* yt4 = (const float4*)y_true;
    const int n4 = n >> 2;  // 4096 float4 groups

    float sa[ROWS], sp[ROWS];
    #pragma unroll
    for (int r = 0; r < ROWS; ++r) { sa[r] = 0.f; sp[r] = 0.f; }

    for (int j = tid; j < n4; j += THREADS) {   // 8 groups/thread
        const float4 yp = yp4[j];
        const float4 yt = yt4[j];
        const float c0 = 1.0f + yp.x, c1 = 1.0f + yp.y;
        const float c2 = 1.0f + yp.z, c3 = 1.0f + yp.w;
        #pragma unroll
        for (int r = 0; r < ROWS; ++r) {
            float m, t;
            m = fmaxf(c0 - f[r], 0.f); sa[r] = fmaf(m, m, sa[r]); t = m * yt.x; sp[r] = fmaf(t, m, sp[r]);
            m = fmaxf(c1 - f[r], 0.f); sa[r] = fmaf(m, m, sa[r]); t = m * yt.y; sp[r] = fmaf(t, m, sp[r]);
            m = fmaxf(c2 - f[r], 0.f); sa[r] = fmaf(m, m, sa[r]); t = m * yt.z; sp[r] = fmaf(t, m, sp[r]);
            m = fmaxf(c3 - f[r], 0.f); sa[r] = fmaf(m, m, sa[r]); t = m * yt.w; sp[r] = fmaf(t, m, sp[r]);
        }
    }

    // wave-64 butterfly reduce (fp32 partials: ~5500 magnitude, rel err ~1e-6)
    #pragma unroll
    for (int off = 32; off > 0; off >>= 1) {
        #pragma unroll
        for (int r = 0; r < ROWS; ++r) {
            sa[r] += __shfl_down(sa[r], off, 64);
            sp[r] += __shfl_down(sp[r], off, 64);
        }
    }

    __shared__ float sh_a[THREADS / 64][ROWS];
    __shared__ float sh_p[THREADS / 64][ROWS];
    const int wave = tid >> 6;
    const int lane = tid & 63;
    if (lane == 0) {
        #pragma unroll
        for (int r = 0; r < ROWS; ++r) { sh_a[wave][r] = sa[r]; sh_p[wave][r] = sp[r]; }
    }
    __syncthreads();

    if (tid < ROWS) {  // thread r finalizes row i0+r in fp64
        double ta = 0.0, tp = 0.0;
        #pragma unroll
        for (int w = 0; w < THREADS / 64; ++w) {
            ta += (double)sh_a[w][tid];
            tp += (double)sh_p[w][tid];
        }
        const int idx = index_s[i0 + tid];
        const double inv_n = 1.0 / (double)n;
        const double ua = 0.01 * (double)u_all[idx] + 0.99 * (ta * inv_n);
        const double up = 0.01 * (double)u_pos[idx] + 0.99 * (tp * inv_n);
        row_out[i0 + tid] = (up * ta - ua * tp) / (ua * ua);
    }
}

__global__ __launch_bounds__(256) void aploss_reduce(
    const double* __restrict__ row_terms,
    float* __restrict__ out,
    int n_pos, int n)
{
    const int tid = threadIdx.x;
    double s = 0.0;
    for (int i = tid; i < n_pos; i += 256) s += row_terms[i];
    #pragma unroll
    for (int off = 32; off > 0; off >>= 1) s += __shfl_down(s, off, 64);

    __shared__ double sh[4];
    const int wave = tid >> 6;
    const int lane = tid & 63;
    if (lane == 0) sh[wave] = s;
    __syncthreads();
    if (tid == 0) {
        double tot = sh[0] + sh[1] + sh[2] + sh[3];
        out[0] = (float)(tot / ((double)n_pos * (double)n));
    }
}

extern "C" void kernel_launch(void* const* d_in, const int* in_sizes, int n_in,
                              void* d_out, int out_size, void* d_ws, size_t ws_size,
                              hipStream_t stream) {
    const float* y_pred  = (const float*)d_in[0];
    const float* y_true  = (const float*)d_in[1];
    const float* u_all   = (const float*)d_in[2];
    const float* u_pos   = (const float*)d_in[3];
    const int*   index_s = (const int*)d_in[4];
    const int n     = in_sizes[0];   // 16384
    const int n_pos = 2048;          // fixed by problem (grid dim is host-side)

    double* row_terms = (double*)d_ws;   // 16 KiB scratch
    float*  out       = (float*)d_out;

    aploss_rows<<<n_pos / ROWS, THREADS, 0, stream>>>(
        y_pred, y_true, u_all, u_pos, index_s, row_terms, n);
    aploss_reduce<<<1, 256, 0, stream>>>(row_terms, out, n_pos, n);
}